// Round 1
// baseline (410.706 us; speedup 1.0000x reference)
//
#include <hip/hip_runtime.h>
#include <stdint.h>
#include <math.h>

#define NB 32  // batch

// ---------------- Threefry-2x32-20 (exact JAX semantics) ----------------
__device__ __forceinline__ void tf_block(uint32_t k0, uint32_t k1, uint32_t& x0, uint32_t& x1) {
  uint32_t k2 = 0x1BD11BDAu ^ k0 ^ k1;
  x0 += k0; x1 += k1;
#define TFR(r) { x0 += x1; x1 = (x1 << r) | (x1 >> (32 - r)); x1 ^= x0; }
  TFR(13) TFR(15) TFR(26) TFR(6)
  x0 += k1; x1 += k2 + 1u;
  TFR(17) TFR(29) TFR(16) TFR(24)
  x0 += k2; x1 += k0 + 2u;
  TFR(13) TFR(15) TFR(26) TFR(6)
  x0 += k0; x1 += k1 + 3u;
  TFR(17) TFR(29) TFR(16) TFR(24)
  x0 += k1; x1 += k2 + 4u;
  TFR(13) TFR(15) TFR(26) TFR(6)
  x0 += k2; x1 += k0 + 5u;
#undef TFR
}

__device__ __forceinline__ float sigmoidf(float x) { return 1.0f / (1.0f + expf(-x)); }

// Block reduce (256 threads): wave shuffle + 4-slot LDS. Result valid on thread 0.
__device__ __forceinline__ float block_reduce(float v, float* red) {
  __syncthreads();  // protect red[] reuse
  int lane = threadIdx.x & 63, wv = threadIdx.x >> 6;
  for (int o = 32; o > 0; o >>= 1) v += __shfl_down(v, o, 64);
  if (lane == 0) red[wv] = v;
  __syncthreads();
  float r = 0.f;
  if (threadIdx.x == 0) r = red[0] + red[1] + red[2] + red[3];
  return r;
}

// ---------------- K0: perms + zero the slot accumulators ----------------
__global__ __launch_bounds__(256) void k0_perm(int* idx0, int* idx1, float* ws) {
  __shared__ uint32_t sub[2][2];
  __shared__ uint32_t bits[2][256];
  int t = threadIdx.x;
  for (int i = t; i < 384; i += 256) ws[i] = 0.0f;  // slots + main acc
  if (t == 0) {
    for (int i = 0; i < 2; ++i) {
      uint32_t f0 = 0u, f1 = (uint32_t)i;          // fold_in(key(42), i)
      tf_block(0u, 42u, f0, f1);
      uint32_t a0 = 0u, a1 = 2u; tf_block(f0, f1, a0, a1);   // split -> kt
      uint32_t b0 = 1u, b1 = 3u; tf_block(f0, f1, b0, b1);
      uint32_t kt0 = a1, kt1 = b1;
      uint32_t c0 = 0u, c1 = 2u; tf_block(kt0, kt1, c0, c1); // split inside permutation
      uint32_t d0 = 1u, d1 = 3u; tf_block(kt0, kt1, d0, d1);
      sub[i][0] = c1; sub[i][1] = d1;
    }
  }
  __syncthreads();
  if (t < 128) {
    for (int i = 0; i < 2; ++i) {
      uint32_t x0 = (uint32_t)t, x1 = (uint32_t)(t + 128);
      tf_block(sub[i][0], sub[i][1], x0, x1);
      bits[i][t] = x0; bits[i][t + 128] = x1;
    }
  }
  __syncthreads();
  for (int i = 0; i < 2; ++i) {   // stable ascending rank = lax.sort_key_val
    uint32_t mine = bits[i][t];
    int rank = 0;
    for (int k = 0; k < 256; ++k) {
      uint32_t v = bits[i][k];
      rank += (v < mine) || (v == mine && k < t);
    }
    int lim = (i == 0) ? 64 : 128;
    if (rank < lim) { (i == 0 ? idx0 : idx1)[rank] = t; }
  }
}

// ---------------- K1: pass1 — streaming pixel-chunk blocks ----------------
// Per block: one pixel-chunk, loop over ALL channels. Emits per-channel ssq
// partials (wave-shuffle reduce, no barrier in loop), SCR accumulation
// (teacher read direct from global, L2-hot, coalesced), and per-pixel channel
// totals `tot` (enables weak-half-only pass 2).

template<bool WT>
__device__ __forceinline__ void p1_feat2(const float* __restrict__ f2,
                                         float* __restrict__ ns2p, float* __restrict__ tot2,
                                         int q, float* nsp, int lane, int wv) {
  int b = q >> 1, hf = q & 1;          // half-plane of 512 px, float2/thread
  int t = threadIdx.x;
  const float2* base = (const float2*)(f2 + (size_t)b * 262144 + hf * 512);
  float2 tot = {0.f, 0.f};
  #pragma unroll 4
  for (int c = 0; c < 256; ++c) {
    float2 v = base[c * 512 + t];
    tot.x += v.x; tot.y += v.y;
    float s = v.x * v.x + v.y * v.y;
    #pragma unroll
    for (int o = 32; o > 0; o >>= 1) s += __shfl_down(s, o, 64);
    if (lane == 0) nsp[c * 4 + wv] = s;
  }
  __syncthreads();
  ns2p[(b * 2 + hf) * 256 + t] = nsp[4 * t] + nsp[4 * t + 1] + nsp[4 * t + 2] + nsp[4 * t + 3];
  if (WT) ((float2*)(tot2 + b * 1024 + hf * 512))[t] = tot;
}

template<bool WT>
__device__ __forceinline__ void p1_feat1(const float* __restrict__ f1, const float* __restrict__ f2,
                                         const int* __restrict__ idx1,
                                         float* __restrict__ ns1p, float* __restrict__ scr1_s,
                                         float* __restrict__ tot1,
                                         int q, float* nsp, int* sidx, float* red, int lane, int wv) {
  int b = q >> 2, chunk = q & 3;       // 1024-px chunk = 16 rows of 64
  int t = threadIdx.x;
  if (t < 128) sidx[t] = idx1[t];
  __syncthreads();
  const float4* base = (const float4*)(f1 + (size_t)b * 524288 + chunk * 1024);
  int th = chunk * 8 + (t >> 5);       // teacher row = student row >> 1
  const float* tbase = f2 + (size_t)b * 262144 + th * 32 + (t & 15) * 2;
  float4 tot = {0.f, 0.f, 0.f, 0.f};
  float scr = 0.f;
  #pragma unroll 4
  for (int c = 0; c < 128; ++c) {
    float4 v = base[c * 1024 + t];
    float2 tv = *(const float2*)(tbase + (size_t)sidx[c] * 1024);
    tot.x += v.x; tot.y += v.y; tot.z += v.z; tot.w += v.w;
    float s = v.x * v.x + v.y * v.y + v.z * v.z + v.w * v.w;
    float dx = v.x - tv.x, dy = v.y - tv.x, dz = v.z - tv.y, dw = v.w - tv.y;
    scr += dx * dx + dy * dy + dz * dz + dw * dw;
    #pragma unroll
    for (int o = 32; o > 0; o >>= 1) s += __shfl_down(s, o, 64);
    if (lane == 0) nsp[c * 4 + wv] = s;
  }
  __syncthreads();
  if (t < 128) ns1p[(b * 4 + chunk) * 128 + t] =
      nsp[4 * t] + nsp[4 * t + 1] + nsp[4 * t + 2] + nsp[4 * t + 3];
  if (WT) ((float4*)(tot1 + (size_t)b * 4096 + chunk * 1024))[t] = tot;
  float r = block_reduce(scr, red);
  if (t == 0) atomicAdd(&scr1_s[q & 63], r);
}

template<bool WT>
__device__ __forceinline__ void p1_feat0(const float* __restrict__ f0, const float* __restrict__ f2,
                                         const int* __restrict__ idx0,
                                         float* __restrict__ ns0p, float* __restrict__ scr0_s,
                                         float* __restrict__ tot0,
                                         int q, float* nsp, int* sidx, float* red, int lane, int wv) {
  int b = q >> 4, chunk = q & 15;      // 1024-px chunk = 8 rows of 128
  int t = threadIdx.x;
  if (t < 64) sidx[t] = idx0[t];
  __syncthreads();
  const float4* base = (const float4*)(f0 + (size_t)b * 1048576 + chunk * 1024);
  int th = chunk * 2 + (t >> 7);       // teacher row = student row >> 2
  const float* tbase = f2 + (size_t)b * 262144 + th * 32 + (t & 31);
  float4 tot = {0.f, 0.f, 0.f, 0.f};
  float scr = 0.f;
  #pragma unroll 4
  for (int c = 0; c < 64; ++c) {
    float4 v = base[c * 4096 + t];
    float tv = tbase[(size_t)sidx[c] * 1024];
    tot.x += v.x; tot.y += v.y; tot.z += v.z; tot.w += v.w;
    float s = v.x * v.x + v.y * v.y + v.z * v.z + v.w * v.w;
    float dx = v.x - tv, dy = v.y - tv, dz = v.z - tv, dw = v.w - tv;
    scr += dx * dx + dy * dy + dz * dz + dw * dw;
    #pragma unroll
    for (int o = 32; o > 0; o >>= 1) s += __shfl_down(s, o, 64);
    if (lane == 0) nsp[c * 4 + wv] = s;
  }
  __syncthreads();
  if (t < 64) ns0p[(b * 16 + chunk) * 64 + t] =
      nsp[4 * t] + nsp[4 * t + 1] + nsp[4 * t + 2] + nsp[4 * t + 3];
  if (WT) ((float4*)(tot0 + (size_t)b * 16384 + chunk * 1024))[t] = tot;
  float r = block_reduce(scr, red);
  if (t == 0) atomicAdd(&scr0_s[q & 63], r);
}

template<bool WT>
__global__ __launch_bounds__(256) void k1_pass1(
    const float* __restrict__ f0, const float* __restrict__ f1, const float* __restrict__ f2,
    const int* __restrict__ idx0, const int* __restrict__ idx1,
    float* __restrict__ ns0p, float* __restrict__ ns1p, float* __restrict__ ns2p,
    float* __restrict__ scr0_s, float* __restrict__ scr1_s,
    float* __restrict__ tot0, float* __restrict__ tot1, float* __restrict__ tot2) {
  __shared__ float nsp[1024];
  __shared__ int sidx[128];
  __shared__ float red[8];
  int bid = blockIdx.x;
  int lane = threadIdx.x & 63, wv = threadIdx.x >> 6;
  if (bid < 64)       p1_feat2<WT>(f2, ns2p, tot2, bid, nsp, lane, wv);
  else if (bid < 192) p1_feat1<WT>(f1, f2, idx1, ns1p, scr1_s, tot1, bid - 64, nsp, sidx, red, lane, wv);
  else                p1_feat0<WT>(f0, f2, idx0, ns0p, scr0_s, tot0, bid - 192, nsp, sidx, red, lane, wv);
}

// ---------------- K2: ranks (stable descending) + weak index lists + main loss ----------------
template<int C, int NP>
__device__ __forceinline__ void rank_work(const float* __restrict__ nspg,
                                          int* __restrict__ widx, int b, float* nm) {
  int t = threadIdx.x;
  if (t < C) {
    float s = 0.f;
    #pragma unroll
    for (int p = 0; p < NP; ++p) s += nspg[(b * NP + p) * C + t];
    nm[t] = sqrtf(s);
  }
  __syncthreads();
  if (t < C) {
    float mine = nm[t];
    int rank = 0;
    for (int k = 0; k < C; ++k) {
      float v = nm[k];
      rank += (v > mine) || (v == mine && k < t);
    }
    constexpr int HALF = C / 2;
    if (rank >= HALF) widx[b * HALF + rank - HALF] = t;   // weak = ranks [C/2, C)
  }
}

__device__ __forceinline__ void main_work(const float* __restrict__ pred,
                                          const int* __restrict__ target,
                                          float* acc, int b, float* sh) {
  int t = threadIdx.x;
  const float* row = pred + b * 1000;
  float m = -INFINITY;
  for (int j = t; j < 1000; j += 256) m = fmaxf(m, row[j]);
  sh[t] = m; __syncthreads();
  for (int s = 128; s > 0; s >>= 1) { if (t < s) sh[t] = fmaxf(sh[t], sh[t + s]); __syncthreads(); }
  m = sh[0]; __syncthreads();
  float e = 0.f;
  for (int j = t; j < 1000; j += 256) e += expf(row[j] - m);
  sh[t] = e; __syncthreads();
  for (int s = 128; s > 0; s >>= 1) { if (t < s) sh[t] += sh[t + s]; __syncthreads(); }
  if (t == 0) atomicAdd(acc, (logf(sh[0]) + m - row[target[b]]) * (1.0f / 32.0f));
}

__global__ __launch_bounds__(256) void k2_rank_main(
    const float* __restrict__ ns0p, const float* __restrict__ ns1p, const float* __restrict__ ns2p,
    int* __restrict__ widx0, int* __restrict__ widx1, int* __restrict__ widx2,
    const float* __restrict__ pred, const int* __restrict__ target, float* __restrict__ main_acc) {
  __shared__ float sh[256];
  int bid = blockIdx.x;
  if (bid < 32)       rank_work<64, 16>(ns0p, widx0, bid, sh);
  else if (bid < 64)  rank_work<128, 4>(ns1p, widx1, bid - 32, sh);
  else if (bid < 96)  rank_work<256, 2>(ns2p, widx2, bid - 64, sh);
  else                main_work(pred, target, main_acc, bid - 96, sh);
}

// ---------------- K3: pass2 (IFD) — weak-half only (strong = tot - weak) ----------------
template<int C, int NCHUNK, bool WT>
__device__ __forceinline__ void ifd_vec4(const float* __restrict__ feat,
                                         const int* __restrict__ widx,
                                         const float* __restrict__ tot,
                                         float* __restrict__ slots,
                                         int q, int* swx, float* wf, float* red) {
  constexpr int HALF = C / 2;
  constexpr int HW = NCHUNK * 1024;
  const float ih = 1.0f / (float)HALF;
  int b = q / NCHUNK, chunk = q % NCHUNK;
  int t = threadIdx.x;
  const float4* base = (const float4*)(feat + (size_t)b * C * HW + chunk * 1024);
  float4 wk = {0.f, 0.f, 0.f, 0.f};
  float4 tt = {0.f, 0.f, 0.f, 0.f};
  if (WT) {
    if (t < HALF) swx[t] = widx[b * HALF + t];
    __syncthreads();
    #pragma unroll 4
    for (int i = 0; i < HALF; ++i) {
      float4 v = base[swx[i] * (HW / 4) + t];
      wk.x += v.x; wk.y += v.y; wk.z += v.z; wk.w += v.w;
    }
    tt = ((const float4*)(tot + (size_t)b * HW + chunk * 1024))[t];
  } else {
    for (int c = t; c < C; c += 256) wf[c] = 0.f;
    __syncthreads();
    if (t < HALF) wf[widx[b * HALF + t]] = 1.f;
    __syncthreads();
    #pragma unroll 2
    for (int c = 0; c < C; ++c) {
      float4 v = base[c * (HW / 4) + t];
      float f = wf[c];
      tt.x += v.x; tt.y += v.y; tt.z += v.z; tt.w += v.w;
      wk.x = fmaf(v.x, f, wk.x); wk.y = fmaf(v.y, f, wk.y);
      wk.z = fmaf(v.z, f, wk.z); wk.w = fmaf(v.w, f, wk.w);
    }
  }
  float s = 0.f, d;
  d = sigmoidf(wk.x * ih) - sigmoidf((tt.x - wk.x) * ih); s += d * d;
  d = sigmoidf(wk.y * ih) - sigmoidf((tt.y - wk.y) * ih); s += d * d;
  d = sigmoidf(wk.z * ih) - sigmoidf((tt.z - wk.z) * ih); s += d * d;
  d = sigmoidf(wk.w * ih) - sigmoidf((tt.w - wk.w) * ih); s += d * d;
  float r = block_reduce(s, red);
  if (t == 0) atomicAdd(&slots[q & 63], r);
}

template<bool WT>
__device__ __forceinline__ void ifd_feat2(const float* __restrict__ f2,
                                          const int* __restrict__ widx2,
                                          const float* __restrict__ tot2,
                                          float* __restrict__ slots,
                                          int q, int* swx, float* wf, float* red) {
  int b = q >> 1, hf = q & 1;
  int t = threadIdx.x;
  const float ih = 1.0f / 128.0f;
  const float2* base = (const float2*)(f2 + (size_t)b * 262144 + hf * 512);
  float2 wk = {0.f, 0.f}, tt = {0.f, 0.f};
  if (WT) {
    if (t < 128) swx[t] = widx2[b * 128 + t];
    __syncthreads();
    #pragma unroll 4
    for (int i = 0; i < 128; ++i) {
      float2 v = base[swx[i] * 512 + t];
      wk.x += v.x; wk.y += v.y;
    }
    tt = ((const float2*)(tot2 + b * 1024 + hf * 512))[t];
  } else {
    wf[t] = 0.f;
    __syncthreads();
    if (t < 128) wf[widx2[b * 128 + t]] = 1.f;
    __syncthreads();
    #pragma unroll 2
    for (int c = 0; c < 256; ++c) {
      float2 v = base[c * 512 + t];
      float f = wf[c];
      tt.x += v.x; tt.y += v.y;
      wk.x = fmaf(v.x, f, wk.x); wk.y = fmaf(v.y, f, wk.y);
    }
  }
  float s = 0.f, d;
  d = sigmoidf(wk.x * ih) - sigmoidf((tt.x - wk.x) * ih); s += d * d;
  d = sigmoidf(wk.y * ih) - sigmoidf((tt.y - wk.y) * ih); s += d * d;
  float r = block_reduce(s, red);
  if (t == 0) atomicAdd(&slots[q & 63], r);
}

template<bool WT>
__global__ __launch_bounds__(256) void k3_pass2(
    const float* __restrict__ f0, const float* __restrict__ f1, const float* __restrict__ f2,
    const int* __restrict__ widx0, const int* __restrict__ widx1, const int* __restrict__ widx2,
    const float* __restrict__ tot0, const float* __restrict__ tot1, const float* __restrict__ tot2,
    float* __restrict__ ifd0_s, float* __restrict__ ifd1_s, float* __restrict__ ifd2_s) {
  __shared__ int swx[128];
  __shared__ float wf[256];
  __shared__ float red[8];
  int bid = blockIdx.x;
  if (bid < 64)       ifd_feat2<WT>(f2, widx2, tot2, ifd2_s, bid, swx, wf, red);
  else if (bid < 192) ifd_vec4<128, 4, WT>(f1, widx1, tot1, ifd1_s, bid - 64, swx, wf, red);
  else                ifd_vec4<64, 16, WT>(f0, widx0, tot0, ifd0_s, bid - 192, swx, wf, red);
}

// ---------------- K4: finalize ----------------
__global__ void k4_finalize(const float* __restrict__ ws, float* __restrict__ out) {
  float scr0 = 0.f, scr1 = 0.f, ifd0 = 0.f, ifd1 = 0.f, ifd2 = 0.f;
  for (int i = 0; i < 64; ++i) {
    scr0 += ws[i];       scr1 += ws[64 + i];
    ifd0 += ws[128 + i]; ifd1 += ws[192 + i]; ifd2 += ws[256 + i];
  }
  float l_main = ws[320];
  scr0 *= (1.0f / (32.0f * 64.0f * 128.0f * 128.0f));
  scr1 *= (1.0f / (32.0f * 128.0f * 64.0f * 64.0f));
  float l_scr = 0.5f * (scr0 + scr1);
  ifd0 *= (1.0f / (32.0f * 128.0f * 128.0f));
  ifd1 *= (1.0f / (32.0f * 64.0f * 64.0f));
  ifd2 *= (1.0f / (32.0f * 32.0f * 32.0f));
  float l_ifd = (ifd0 + ifd1 + ifd2) * (1.0f / 3.0f);
  float total = l_main + 0.015f * l_scr + 0.015f * l_ifd;
  out[0] = total; out[1] = l_main; out[2] = l_scr; out[3] = l_ifd;
}

extern "C" void kernel_launch(void* const* d_in, const int* in_sizes, int n_in,
                              void* d_out, int out_size, void* d_ws, size_t ws_size,
                              hipStream_t stream) {
  (void)in_sizes; (void)n_in; (void)out_size;
  const float* pred   = (const float*)d_in[0];
  const float* feat0  = (const float*)d_in[1];  // 32 x 64 x 128 x 128
  const float* feat1  = (const float*)d_in[2];  // 32 x 128 x 64 x 64
  const float* feat2  = (const float*)d_in[3];  // 32 x 256 x 32 x 32 (teacher)
  const int*   target = (const int*)d_in[4];
  float* out = (float*)d_out;

  // ws layout (floats):
  // [0,64)=scr0 [64,128)=scr1 [128,192)=ifd0 [192,256)=ifd1 [256,320)=ifd2 [320]=main
  float* ws     = (float*)d_ws;
  float* scr0_s = ws;
  float* scr1_s = ws + 64;
  float* ifd0_s = ws + 128;
  float* ifd1_s = ws + 192;
  float* ifd2_s = ws + 256;
  int*   idx0   = (int*)(ws + 384);       // 64
  int*   idx1   = idx0 + 64;              // 128
  int*   widx0  = idx1 + 128;             // 32*32
  int*   widx1  = widx0 + 1024;           // 32*64
  int*   widx2  = widx1 + 2048;           // 32*128
  float* ns0p   = (float*)(widx2 + 4096); // 32*16*64
  float* ns1p   = ns0p + 32768;           // 32*4*128
  float* ns2p   = ns1p + 16384;           // 32*2*256
  float* tot0   = ns2p + 16384;           // 32*16384
  float* tot1   = tot0 + 524288;          // 32*4096
  float* tot2   = tot1 + 131072;          // 32*1024
  const size_t need_full = (size_t)761408 * 4;
  bool wt = (ws_size == 0) || (ws_size >= need_full);

  k0_perm<<<1, 256, 0, stream>>>(idx0, idx1, ws);
  if (wt) {
    k1_pass1<true><<<704, 256, 0, stream>>>(feat0, feat1, feat2, idx0, idx1,
                                            ns0p, ns1p, ns2p, scr0_s, scr1_s, tot0, tot1, tot2);
    k2_rank_main<<<128, 256, 0, stream>>>(ns0p, ns1p, ns2p, widx0, widx1, widx2,
                                          pred, target, ws + 320);
    k3_pass2<true><<<704, 256, 0, stream>>>(feat0, feat1, feat2, widx0, widx1, widx2,
                                            tot0, tot1, tot2, ifd0_s, ifd1_s, ifd2_s);
  } else {
    k1_pass1<false><<<704, 256, 0, stream>>>(feat0, feat1, feat2, idx0, idx1,
                                             ns0p, ns1p, ns2p, scr0_s, scr1_s, tot0, tot1, tot2);
    k2_rank_main<<<128, 256, 0, stream>>>(ns0p, ns1p, ns2p, widx0, widx1, widx2,
                                          pred, target, ws + 320);
    k3_pass2<false><<<704, 256, 0, stream>>>(feat0, feat1, feat2, widx0, widx1, widx2,
                                             tot0, tot1, tot2, ifd0_s, ifd1_s, ifd2_s);
  }
  k4_finalize<<<1, 1, 0, stream>>>(ws, out);
}

// Round 2
// 313.519 us; speedup vs baseline: 1.3100x; 1.3100x over previous
//
#include <hip/hip_runtime.h>
#include <stdint.h>
#include <math.h>

// ---------------- Threefry-2x32-20 (exact JAX semantics) ----------------
__device__ __forceinline__ void tf_block(uint32_t k0, uint32_t k1, uint32_t& x0, uint32_t& x1) {
  uint32_t k2 = 0x1BD11BDAu ^ k0 ^ k1;
  x0 += k0; x1 += k1;
#define TFR(r) { x0 += x1; x1 = (x1 << r) | (x1 >> (32 - r)); x1 ^= x0; }
  TFR(13) TFR(15) TFR(26) TFR(6)
  x0 += k1; x1 += k2 + 1u;
  TFR(17) TFR(29) TFR(16) TFR(24)
  x0 += k2; x1 += k0 + 2u;
  TFR(13) TFR(15) TFR(26) TFR(6)
  x0 += k0; x1 += k1 + 3u;
  TFR(17) TFR(29) TFR(16) TFR(24)
  x0 += k1; x1 += k2 + 4u;
  TFR(13) TFR(15) TFR(26) TFR(6)
  x0 += k2; x1 += k0 + 5u;
#undef TFR
}

__device__ __forceinline__ float sigmoidf(float x) { return 1.0f / (1.0f + expf(-x)); }

// Block reduce (256 threads): wave shuffle + 4-slot LDS. Result valid on thread 0.
__device__ __forceinline__ float block_reduce(float v, float* red) {
  __syncthreads();  // protect red[] reuse
  int lane = threadIdx.x & 63, wv = threadIdx.x >> 6;
  for (int o = 32; o > 0; o >>= 1) v += __shfl_down(v, o, 64);
  if (lane == 0) red[wv] = v;
  __syncthreads();
  float r = 0.f;
  if (threadIdx.x == 0) r = red[0] + red[1] + red[2] + red[3];
  return r;
}

// ---------------- K0: perms + zero slots + zero tot buffers ----------------
// block 0: perm + zero ws[0,384). blocks 1..672: zero the 688128-float tot region.
__global__ __launch_bounds__(256) void k0_perm(int* idx0, int* idx1, float* ws, float* totz) {
  int t = threadIdx.x;
  if (blockIdx.x > 0) {
    float4 z = {0.f, 0.f, 0.f, 0.f};
    ((float4*)totz)[(blockIdx.x - 1) * 256 + t] = z;  // 672*256*4 = 688128 floats
    return;
  }
  __shared__ uint32_t sub[2][2];
  __shared__ uint32_t bits[2][256];
  for (int i = t; i < 384; i += 256) ws[i] = 0.0f;  // slots + main acc
  if (t == 0) {
    for (int i = 0; i < 2; ++i) {
      uint32_t f0 = 0u, f1 = (uint32_t)i;          // fold_in(key(42), i)
      tf_block(0u, 42u, f0, f1);
      uint32_t a0 = 0u, a1 = 2u; tf_block(f0, f1, a0, a1);   // split -> kt
      uint32_t b0 = 1u, b1 = 3u; tf_block(f0, f1, b0, b1);
      uint32_t kt0 = a1, kt1 = b1;
      uint32_t c0 = 0u, c1 = 2u; tf_block(kt0, kt1, c0, c1); // split inside permutation
      uint32_t d0 = 1u, d1 = 3u; tf_block(kt0, kt1, d0, d1);
      sub[i][0] = c1; sub[i][1] = d1;
    }
  }
  __syncthreads();
  if (t < 128) {
    for (int i = 0; i < 2; ++i) {
      uint32_t x0 = (uint32_t)t, x1 = (uint32_t)(t + 128);
      tf_block(sub[i][0], sub[i][1], x0, x1);
      bits[i][t] = x0; bits[i][t + 128] = x1;
    }
  }
  __syncthreads();
  for (int i = 0; i < 2; ++i) {   // stable ascending rank = lax.sort_key_val
    uint32_t mine = bits[i][t];
    int rank = 0;
    for (int k = 0; k < 256; ++k) {
      uint32_t v = bits[i][k];
      rank += (v < mine) || (v == mine && k < t);
    }
    int lim = (i == 0) ? 64 : 128;
    if (rank < lim) { (i == 0 ? idx0 : idx1)[rank] = t; }
  }
}

// ---------------- K1: pass1 ----------------
// Block = (batch, 1024-px chunk, 16-channel group). Each thread: exactly one
// float4 per channel -> 16 fully-independent loads in flight. Per-channel ssq
// via stride-1 LDS store + one end-of-block cross-wave reduce. Per-pixel
// channel totals accumulated with atomicAdd across channel-groups (WT only).
template<bool WT>
__global__ __launch_bounds__(256) void k1_pass1(
    const float* __restrict__ f0, const float* __restrict__ f1, const float* __restrict__ f2,
    const int* __restrict__ idx0, const int* __restrict__ idx1,
    float* __restrict__ ns0p, float* __restrict__ ns1p, float* __restrict__ ns2p,
    float* __restrict__ scr0_s, float* __restrict__ scr1_s,
    float* __restrict__ tot0, float* __restrict__ tot1, float* __restrict__ tot2) {
  __shared__ float nsp[16 * 256];
  __shared__ int sidx[128];
  __shared__ float red[8];
  int bid = blockIdx.x, t = threadIdx.x;
  int lane = t & 63, wv = t >> 6;

  if (bid < 2048) {
    // ---- feat0: 32 x 64 x 128x128 ----
    int q = bid, b = q >> 6, r = q & 63, chunk = r >> 2, cg = r & 3;
    if (t < 64) sidx[t] = idx0[t];
    __syncthreads();
    const float* fb = f0 + (size_t)b * 1048576 + (size_t)cg * 16 * 16384 + chunk * 1024;
    const float* tb = f2 + (size_t)b * 262144 + (chunk * 2 + (t >> 7)) * 32 + (t & 31);
    float4 tot = {0.f, 0.f, 0.f, 0.f};
    float scr = 0.f;
    #pragma unroll
    for (int c = 0; c < 16; ++c) {
      float4 v = ((const float4*)(fb + (size_t)c * 16384))[t];
      float tv = tb[(size_t)sidx[cg * 16 + c] * 1024];
      tot.x += v.x; tot.y += v.y; tot.z += v.z; tot.w += v.w;
      nsp[c * 256 + t] = v.x * v.x + v.y * v.y + v.z * v.z + v.w * v.w;
      float dx = v.x - tv, dy = v.y - tv, dz = v.z - tv, dw = v.w - tv;
      scr += dx * dx + dy * dy + dz * dz + dw * dw;
    }
    __syncthreads();
    #pragma unroll
    for (int j = 0; j < 4; ++j) {
      int c = wv * 4 + j;
      float s = nsp[c * 256 + lane] + nsp[c * 256 + lane + 64] +
                nsp[c * 256 + lane + 128] + nsp[c * 256 + lane + 192];
      #pragma unroll
      for (int o = 32; o > 0; o >>= 1) s += __shfl_down(s, o, 64);
      if (lane == 0) ns0p[(b * 16 + chunk) * 64 + cg * 16 + c] = s;
    }
    if (WT) {
      float* tp = tot0 + (size_t)b * 16384 + chunk * 1024 + t * 4;
      atomicAdd(tp, tot.x); atomicAdd(tp + 1, tot.y);
      atomicAdd(tp + 2, tot.z); atomicAdd(tp + 3, tot.w);
    }
    float rr = block_reduce(scr, red);
    if (t == 0) atomicAdd(&scr0_s[q & 63], rr);

  } else if (bid < 3072) {
    // ---- feat1: 32 x 128 x 64x64 ----
    int q = bid - 2048, b = q >> 5, r = q & 31, chunk = r >> 3, cg = r & 7;
    if (t < 128) sidx[t] = idx1[t];
    __syncthreads();
    const float* fb = f1 + (size_t)b * 524288 + (size_t)cg * 16 * 4096 + chunk * 1024;
    const float* tb = f2 + (size_t)b * 262144 + (chunk * 8 + (t >> 5)) * 32 + (t & 15) * 2;
    float4 tot = {0.f, 0.f, 0.f, 0.f};
    float scr = 0.f;
    #pragma unroll
    for (int c = 0; c < 16; ++c) {
      float4 v = ((const float4*)(fb + (size_t)c * 4096))[t];
      float2 tv = *(const float2*)(tb + (size_t)sidx[cg * 16 + c] * 1024);
      tot.x += v.x; tot.y += v.y; tot.z += v.z; tot.w += v.w;
      nsp[c * 256 + t] = v.x * v.x + v.y * v.y + v.z * v.z + v.w * v.w;
      float dx = v.x - tv.x, dy = v.y - tv.x, dz = v.z - tv.y, dw = v.w - tv.y;
      scr += dx * dx + dy * dy + dz * dz + dw * dw;
    }
    __syncthreads();
    #pragma unroll
    for (int j = 0; j < 4; ++j) {
      int c = wv * 4 + j;
      float s = nsp[c * 256 + lane] + nsp[c * 256 + lane + 64] +
                nsp[c * 256 + lane + 128] + nsp[c * 256 + lane + 192];
      #pragma unroll
      for (int o = 32; o > 0; o >>= 1) s += __shfl_down(s, o, 64);
      if (lane == 0) ns1p[(b * 4 + chunk) * 128 + cg * 16 + c] = s;
    }
    if (WT) {
      float* tp = tot1 + (size_t)b * 4096 + chunk * 1024 + t * 4;
      atomicAdd(tp, tot.x); atomicAdd(tp + 1, tot.y);
      atomicAdd(tp + 2, tot.z); atomicAdd(tp + 3, tot.w);
    }
    float rr = block_reduce(scr, red);
    if (t == 0) atomicAdd(&scr1_s[q & 63], rr);

  } else {
    // ---- feat2 (teacher): 32 x 256 x 32x32 ----
    int q = bid - 3072, b = q >> 4, cg = q & 15;
    const float* fb = f2 + (size_t)b * 262144 + (size_t)cg * 16 * 1024;
    float4 tot = {0.f, 0.f, 0.f, 0.f};
    #pragma unroll
    for (int c = 0; c < 16; ++c) {
      float4 v = ((const float4*)(fb + (size_t)c * 1024))[t];
      tot.x += v.x; tot.y += v.y; tot.z += v.z; tot.w += v.w;
      nsp[c * 256 + t] = v.x * v.x + v.y * v.y + v.z * v.z + v.w * v.w;
    }
    __syncthreads();
    #pragma unroll
    for (int j = 0; j < 4; ++j) {
      int c = wv * 4 + j;
      float s = nsp[c * 256 + lane] + nsp[c * 256 + lane + 64] +
                nsp[c * 256 + lane + 128] + nsp[c * 256 + lane + 192];
      #pragma unroll
      for (int o = 32; o > 0; o >>= 1) s += __shfl_down(s, o, 64);
      if (lane == 0) ns2p[b * 256 + cg * 16 + c] = s;
    }
    if (WT) {
      float* tp = tot2 + (size_t)b * 1024 + t * 4;
      atomicAdd(tp, tot.x); atomicAdd(tp + 1, tot.y);
      atomicAdd(tp + 2, tot.z); atomicAdd(tp + 3, tot.w);
    }
  }
}

// ---------------- K2: ranks (stable descending) + weak lists + main loss ----------------
template<int C, int NP>
__device__ __forceinline__ void rank_work(const float* __restrict__ nspg,
                                          int* __restrict__ widx, int b, float* nm) {
  int t = threadIdx.x;
  if (t < C) {
    float s = 0.f;
    #pragma unroll
    for (int p = 0; p < NP; ++p) s += nspg[(b * NP + p) * C + t];
    nm[t] = sqrtf(s);
  }
  __syncthreads();
  if (t < C) {
    float mine = nm[t];
    int rank = 0;
    for (int k = 0; k < C; ++k) {
      float v = nm[k];
      rank += (v > mine) || (v == mine && k < t);
    }
    constexpr int HALF = C / 2;
    if (rank >= HALF) widx[b * HALF + rank - HALF] = t;   // weak = ranks [C/2, C)
  }
}

__device__ __forceinline__ void main_work(const float* __restrict__ pred,
                                          const int* __restrict__ target,
                                          float* acc, int b, float* sh) {
  int t = threadIdx.x;
  const float* row = pred + b * 1000;
  float m = -INFINITY;
  for (int j = t; j < 1000; j += 256) m = fmaxf(m, row[j]);
  sh[t] = m; __syncthreads();
  for (int s = 128; s > 0; s >>= 1) { if (t < s) sh[t] = fmaxf(sh[t], sh[t + s]); __syncthreads(); }
  m = sh[0]; __syncthreads();
  float e = 0.f;
  for (int j = t; j < 1000; j += 256) e += expf(row[j] - m);
  sh[t] = e; __syncthreads();
  for (int s = 128; s > 0; s >>= 1) { if (t < s) sh[t] += sh[t + s]; __syncthreads(); }
  if (t == 0) atomicAdd(acc, (logf(sh[0]) + m - row[target[b]]) * (1.0f / 32.0f));
}

__global__ __launch_bounds__(256) void k2_rank_main(
    const float* __restrict__ ns0p, const float* __restrict__ ns1p, const float* __restrict__ ns2p,
    int* __restrict__ widx0, int* __restrict__ widx1, int* __restrict__ widx2,
    const float* __restrict__ pred, const int* __restrict__ target, float* __restrict__ main_acc) {
  __shared__ float sh[256];
  int bid = blockIdx.x;
  if (bid < 32)       rank_work<64, 16>(ns0p, widx0, bid, sh);
  else if (bid < 64)  rank_work<128, 4>(ns1p, widx1, bid - 32, sh);
  else if (bid < 96)  rank_work<256, 1>(ns2p, widx2, bid - 64, sh);
  else                main_work(pred, target, main_acc, bid - 96, sh);
}

// ---------------- K3: pass2 (IFD) — weak half only (strong = tot - weak) ----------------
// Block = (batch, 512-px chunk); float2 per thread per channel; unroll-8 MLP.
template<int C, int HW, bool WT>
__device__ __forceinline__ void ifd_work(const float* __restrict__ feat,
                                         const int* __restrict__ widx,
                                         const float* __restrict__ tot,
                                         float* __restrict__ slots,
                                         int q, int* swx, float* wf, float* red) {
  constexpr int HALF = C / 2;
  constexpr int S2 = HW / 2;        // channel stride in float2
  constexpr int NCH = HW / 512;     // chunks per plane
  const float ih = 1.0f / (float)HALF;
  int b = q / NCH, ch = q % NCH;
  int t = threadIdx.x;
  const float2* base2 = (const float2*)(feat + (size_t)b * C * HW + ch * 512);
  float2 wk = {0.f, 0.f}, tt = {0.f, 0.f};
  if (WT) {
    if (t < HALF) swx[t] = widx[b * HALF + t];
    __syncthreads();
    #pragma unroll 8
    for (int i = 0; i < HALF; ++i) {
      float2 v = base2[(size_t)swx[i] * S2 + t];
      wk.x += v.x; wk.y += v.y;
    }
    tt = ((const float2*)(tot + (size_t)b * HW + ch * 512))[t];
  } else {
    for (int c = t; c < C; c += 256) wf[c] = 0.f;
    __syncthreads();
    if (t < HALF) wf[widx[b * HALF + t]] = 1.f;
    __syncthreads();
    #pragma unroll 4
    for (int c = 0; c < C; ++c) {
      float2 v = base2[(size_t)c * S2 + t];
      float f = wf[c];
      tt.x += v.x; tt.y += v.y;
      wk.x = fmaf(v.x, f, wk.x); wk.y = fmaf(v.y, f, wk.y);
    }
  }
  float s = 0.f, d;
  d = sigmoidf(wk.x * ih) - sigmoidf((tt.x - wk.x) * ih); s += d * d;
  d = sigmoidf(wk.y * ih) - sigmoidf((tt.y - wk.y) * ih); s += d * d;
  float r = block_reduce(s, red);
  if (t == 0) atomicAdd(&slots[q & 63], r);
}

template<bool WT>
__global__ __launch_bounds__(256) void k3_pass2(
    const float* __restrict__ f0, const float* __restrict__ f1, const float* __restrict__ f2,
    const int* __restrict__ widx0, const int* __restrict__ widx1, const int* __restrict__ widx2,
    const float* __restrict__ tot0, const float* __restrict__ tot1, const float* __restrict__ tot2,
    float* __restrict__ ifd0_s, float* __restrict__ ifd1_s, float* __restrict__ ifd2_s) {
  __shared__ int swx[128];
  __shared__ float wf[256];
  __shared__ float red[8];
  int bid = blockIdx.x;
  // heaviest blocks (feat2: 128 ch/block) dispatched first for load balance
  if (bid < 64)        ifd_work<256, 1024, WT>(f2, widx2, tot2, ifd2_s, bid, swx, wf, red);
  else if (bid < 320)  ifd_work<128, 4096, WT>(f1, widx1, tot1, ifd1_s, bid - 64, swx, wf, red);
  else                 ifd_work<64, 16384, WT>(f0, widx0, tot0, ifd0_s, bid - 320, swx, wf, red);
}

// ---------------- K4: finalize ----------------
__global__ void k4_finalize(const float* __restrict__ ws, float* __restrict__ out) {
  float scr0 = 0.f, scr1 = 0.f, ifd0 = 0.f, ifd1 = 0.f, ifd2 = 0.f;
  for (int i = 0; i < 64; ++i) {
    scr0 += ws[i];       scr1 += ws[64 + i];
    ifd0 += ws[128 + i]; ifd1 += ws[192 + i]; ifd2 += ws[256 + i];
  }
  float l_main = ws[320];
  scr0 *= (1.0f / (32.0f * 64.0f * 128.0f * 128.0f));
  scr1 *= (1.0f / (32.0f * 128.0f * 64.0f * 64.0f));
  float l_scr = 0.5f * (scr0 + scr1);
  ifd0 *= (1.0f / (32.0f * 128.0f * 128.0f));
  ifd1 *= (1.0f / (32.0f * 64.0f * 64.0f));
  ifd2 *= (1.0f / (32.0f * 32.0f * 32.0f));
  float l_ifd = (ifd0 + ifd1 + ifd2) * (1.0f / 3.0f);
  float total = l_main + 0.015f * l_scr + 0.015f * l_ifd;
  out[0] = total; out[1] = l_main; out[2] = l_scr; out[3] = l_ifd;
}

extern "C" void kernel_launch(void* const* d_in, const int* in_sizes, int n_in,
                              void* d_out, int out_size, void* d_ws, size_t ws_size,
                              hipStream_t stream) {
  (void)in_sizes; (void)n_in; (void)out_size;
  const float* pred   = (const float*)d_in[0];
  const float* feat0  = (const float*)d_in[1];  // 32 x 64 x 128 x 128
  const float* feat1  = (const float*)d_in[2];  // 32 x 128 x 64 x 64
  const float* feat2  = (const float*)d_in[3];  // 32 x 256 x 32 x 32 (teacher)
  const int*   target = (const int*)d_in[4];
  float* out = (float*)d_out;

  // ws layout (floats):
  // [0,64)=scr0 [64,128)=scr1 [128,192)=ifd0 [192,256)=ifd1 [256,320)=ifd2 [320]=main
  float* ws     = (float*)d_ws;
  float* scr0_s = ws;
  float* scr1_s = ws + 64;
  float* ifd0_s = ws + 128;
  float* ifd1_s = ws + 192;
  float* ifd2_s = ws + 256;
  int*   idx0   = (int*)(ws + 384);       // 64
  int*   idx1   = idx0 + 64;              // 128
  int*   widx0  = idx1 + 128;             // 32*32
  int*   widx1  = widx0 + 1024;           // 32*64
  int*   widx2  = widx1 + 2048;           // 32*128
  float* ns0p   = (float*)(widx2 + 4096); // 32*16*64
  float* ns1p   = ns0p + 32768;           // 32*4*128
  float* ns2p   = ns1p + 16384;           // 32*256
  float* tot0   = ns2p + 8192;            // 32*16384
  float* tot1   = tot0 + 524288;          // 32*4096
  float* tot2   = tot1 + 131072;          // 32*1024  -> end 753216 floats
  const size_t need_full = (size_t)753216 * 4;
  bool wt = (ws_size == 0) || (ws_size >= need_full);

  k0_perm<<<wt ? 673 : 1, 256, 0, stream>>>(idx0, idx1, ws, tot0);
  if (wt) {
    k1_pass1<true><<<3584, 256, 0, stream>>>(feat0, feat1, feat2, idx0, idx1,
                                             ns0p, ns1p, ns2p, scr0_s, scr1_s, tot0, tot1, tot2);
    k2_rank_main<<<128, 256, 0, stream>>>(ns0p, ns1p, ns2p, widx0, widx1, widx2,
                                          pred, target, ws + 320);
    k3_pass2<true><<<1344, 256, 0, stream>>>(feat0, feat1, feat2, widx0, widx1, widx2,
                                             tot0, tot1, tot2, ifd0_s, ifd1_s, ifd2_s);
  } else {
    k1_pass1<false><<<3584, 256, 0, stream>>>(feat0, feat1, feat2, idx0, idx1,
                                              ns0p, ns1p, ns2p, scr0_s, scr1_s, tot0, tot1, tot2);
    k2_rank_main<<<128, 256, 0, stream>>>(ns0p, ns1p, ns2p, widx0, widx1, widx2,
                                          pred, target, ws + 320);
    k3_pass2<false><<<1344, 256, 0, stream>>>(feat0, feat1, feat2, widx0, widx1, widx2,
                                              tot0, tot1, tot2, ifd0_s, ifd1_s, ifd2_s);
  }
  k4_finalize<<<1, 1, 0, stream>>>(ws, out);
}